// Round 2
// baseline (538.609 us; speedup 1.0000x reference)
//
#include <hip/hip_runtime.h>
#include <hip/hip_bf16.h>

#define E_EDGES 500000
#define NN 50000

typedef unsigned short u16;
typedef __attribute__((ext_vector_type(8))) short s16x8;
typedef __attribute__((ext_vector_type(4))) float f32x4;

__device__ __forceinline__ short f2bf(float f) {
    unsigned u = __builtin_bit_cast(unsigned, f);
    u += 0x7fffu + ((u >> 16) & 1u);
    return (short)(u >> 16);
}

__device__ __forceinline__ float lrelu(float x) { return x > 0.0f ? x : 0.01f * x; }

__device__ __forceinline__ s16x8 cvt8(float4 lo, float4 hi) {
    s16x8 w;
    w[0] = f2bf(lo.x); w[1] = f2bf(lo.y); w[2] = f2bf(lo.z); w[3] = f2bf(lo.w);
    w[4] = f2bf(hi.x); w[5] = f2bf(hi.y); w[6] = f2bf(hi.z); w[7] = f2bf(hi.w);
    return w;
}

// ---- weight prep: WT[g][n][k] = bf16(W_g[k][n]), g in {src, tgt, edge} ----
__global__ void kprep(const float* __restrict__ Wsrc, const float* __restrict__ Wtgt,
                      const float* __restrict__ Wedge, u16* __restrict__ WT) {
    int i = blockIdx.x * 256 + threadIdx.x;
    if (i >= 3 * 16384) return;
    int g = i >> 14, nk = i & 16383, n = nk >> 7, k = nk & 127;
    const float* W = (g == 0) ? Wsrc : (g == 1) ? Wtgt : Wedge;
    WT[i] = (u16)f2bf(W[k * 128 + n]);
}

// ---- K1: q = s@Ws + r@Wt + e@We ; z = sum_c leaky(q)*attn ; ez=exp(z); denom atomic ----
// No LDS, no barriers: A fragments loaded straight from global (fp32->bf16 in reg),
// B fragments loaded from the 96 KB L1/L2-resident prepped weights.
__global__ __launch_bounds__(256, 3) void k1(
    const float* __restrict__ recv, const float* __restrict__ send,
    const float* __restrict__ eattr, const int* __restrict__ sidx,
    const u16* __restrict__ WT, const float* __restrict__ attn,
    float* __restrict__ ez, float* __restrict__ denom)
{
    int tid = threadIdx.x;
    int lane = tid & 63, wv = tid >> 6;
    int l15 = lane & 15, lg = lane >> 4;
    int blockRow = blockIdx.x * 128;

    // A rows this lane feeds (m=0 and m=1 sub-tiles); clamp for safe loads
    int rA0 = blockRow + wv * 32 + l15;
    int rA1 = rA0 + 16;
    size_t offA0 = (size_t)min(rA0, E_EDGES - 1) * 128;
    size_t offA1 = (size_t)min(rA1, E_EDGES - 1) * 128;

    f32x4 acc[2][8];
#pragma unroll
    for (int m = 0; m < 2; ++m)
#pragma unroll
        for (int n = 0; n < 8; ++n) acc[m][n] = (f32x4){0.f, 0.f, 0.f, 0.f};

#pragma unroll
    for (int g = 0; g < 3; ++g) {
        const float* X = (g == 0) ? send : (g == 1) ? recv : eattr;
        const u16* Bg = WT + g * 16384;
#pragma unroll
        for (int kk = 0; kk < 4; ++kk) {
            int k0 = kk * 32 + lg * 8;
            float4 a0l = *(const float4*)(X + offA0 + k0);
            float4 a0h = *(const float4*)(X + offA0 + k0 + 4);
            float4 a1l = *(const float4*)(X + offA1 + k0);
            float4 a1h = *(const float4*)(X + offA1 + k0 + 4);
            s16x8 a0 = cvt8(a0l, a0h);
            s16x8 a1 = cvt8(a1l, a1h);
#pragma unroll
            for (int n = 0; n < 8; ++n) {
                s16x8 b = *(const s16x8*)(Bg + (n * 16 + l15) * 128 + k0);
                acc[0][n] = __builtin_amdgcn_mfma_f32_16x16x32_bf16(a0, b, acc[0][n], 0, 0, 0);
                acc[1][n] = __builtin_amdgcn_mfma_f32_16x16x32_bf16(a1, b, acc[1][n], 0, 0, 0);
            }
        }
    }

    float av[8];
#pragma unroll
    for (int n = 0; n < 8; ++n) av[n] = attn[n * 16 + l15];

#pragma unroll
    for (int m = 0; m < 2; ++m) {
#pragma unroll
        for (int h = 0; h < 4; ++h) {
            float part[4];
#pragma unroll
            for (int j = 0; j < 4; ++j)
                part[j] = lrelu(acc[m][2 * h][j]) * av[2 * h] +
                          lrelu(acc[m][2 * h + 1][j]) * av[2 * h + 1];
#pragma unroll
            for (int off = 1; off < 16; off <<= 1) {
#pragma unroll
                for (int j = 0; j < 4; ++j) part[j] += __shfl_xor(part[j], off, 64);
            }
            if (l15 == h) {
#pragma unroll
                for (int j = 0; j < 4; ++j) {
                    int r = blockRow + wv * 32 + m * 16 + lg * 4 + j;
                    if (r < E_EDGES) {
                        float ezv = __expf(part[j]);
                        ez[(size_t)r * 4 + h] = ezv;
                        atomicAdd(&denom[(size_t)sidx[r] * 4 + h], ezv);
                    }
                }
            }
        }
    }
}

// ---- K2: t = r@Wt ; a = ez/denom[sidx] ; out1 = 0.25*sum_h t*a ; out0 atomic seg-sum ----
__global__ __launch_bounds__(256, 3) void k2(
    const float* __restrict__ recv, const int* __restrict__ ridx,
    const int* __restrict__ sidx, const u16* __restrict__ WTt,
    const float* __restrict__ ez, const float* __restrict__ denom,
    float* __restrict__ out0, float* __restrict__ out1)
{
    int tid = threadIdx.x;
    int lane = tid & 63, wv = tid >> 6;
    int l15 = lane & 15, lg = lane >> 4;
    int blockRow = blockIdx.x * 128;

    int rA0 = blockRow + wv * 32 + l15;
    int rA1 = rA0 + 16;
    size_t offA0 = (size_t)min(rA0, E_EDGES - 1) * 128;
    size_t offA1 = (size_t)min(rA1, E_EDGES - 1) * 128;

    f32x4 acc[2][8];
#pragma unroll
    for (int m = 0; m < 2; ++m)
#pragma unroll
        for (int n = 0; n < 8; ++n) acc[m][n] = (f32x4){0.f, 0.f, 0.f, 0.f};

#pragma unroll
    for (int kk = 0; kk < 4; ++kk) {
        int k0 = kk * 32 + lg * 8;
        float4 a0l = *(const float4*)(recv + offA0 + k0);
        float4 a0h = *(const float4*)(recv + offA0 + k0 + 4);
        float4 a1l = *(const float4*)(recv + offA1 + k0);
        float4 a1h = *(const float4*)(recv + offA1 + k0 + 4);
        s16x8 a0 = cvt8(a0l, a0h);
        s16x8 a1 = cvt8(a1l, a1h);
#pragma unroll
        for (int n = 0; n < 8; ++n) {
            s16x8 b = *(const s16x8*)(WTt + (n * 16 + l15) * 128 + k0);
            acc[0][n] = __builtin_amdgcn_mfma_f32_16x16x32_bf16(a0, b, acc[0][n], 0, 0, 0);
            acc[1][n] = __builtin_amdgcn_mfma_f32_16x16x32_bf16(a1, b, acc[1][n], 0, 0, 0);
        }
    }

#pragma unroll
    for (int m = 0; m < 2; ++m) {
#pragma unroll
        for (int j = 0; j < 4; ++j) {
            int r = blockRow + wv * 32 + m * 16 + lg * 4 + j;
            if (r < E_EDGES) {
                int s = sidx[r];
                float4 ezv = *(const float4*)(ez + (size_t)r * 4);
                float4 dn = *(const float4*)(denom + (size_t)s * 4);
                float4 av = {ezv.x / dn.x, ezv.y / dn.y, ezv.z / dn.z, ezv.w / dn.w};
                float lo = 0.25f * (acc[m][0][j] * av.x + acc[m][2][j] * av.y +
                                    acc[m][4][j] * av.z + acc[m][6][j] * av.w);
                float hi = 0.25f * (acc[m][1][j] * av.x + acc[m][3][j] * av.y +
                                    acc[m][5][j] * av.z + acc[m][7][j] * av.w);
                out1[(size_t)r * 32 + l15] = lo;
                out1[(size_t)r * 32 + 16 + l15] = hi;
                int rv = ridx[r];
                atomicAdd(&out0[(size_t)rv * 32 + l15], lo);
                atomicAdd(&out0[(size_t)rv * 32 + 16 + l15], hi);
            }
        }
    }
}

extern "C" void kernel_launch(void* const* d_in, const int* in_sizes, int n_in,
                              void* d_out, int out_size, void* d_ws, size_t ws_size,
                              hipStream_t stream) {
    const float* recv  = (const float*)d_in[0];
    const float* send  = (const float*)d_in[1];
    const float* eattr = (const float*)d_in[2];
    const int*   sidx  = (const int*)d_in[3];
    const int*   ridx  = (const int*)d_in[4];
    const float* Wsrc  = (const float*)d_in[5];
    const float* Wtgt  = (const float*)d_in[6];
    const float* Wedge = (const float*)d_in[7];
    const float* attn  = (const float*)d_in[8];

    char* ws = (char*)d_ws;
    u16*   WT    = (u16*)ws;                         // 3*128*128*2 = 98304 B
    float* ez    = (float*)(ws + 131072);            // E*4*4 = 8,000,000 B
    float* denom = (float*)(ws + 131072 + 8000000);  // N*4*4 = 800,000 B

    float* out0 = (float*)d_out;                     // [N,32]
    float* out1 = out0 + (size_t)NN * 32;            // [E,32]

    hipMemsetAsync(denom, 0, (size_t)NN * 4 * sizeof(float), stream);
    hipMemsetAsync(out0, 0, (size_t)NN * 32 * sizeof(float), stream);

    kprep<<<192, 256, 0, stream>>>(Wsrc, Wtgt, Wedge, WT);

    int nb = (E_EDGES + 127) / 128;  // 3907
    k1<<<nb, 256, 0, stream>>>(recv, send, eattr, sidx, WT, attn, ez, denom);
    k2<<<nb, 256, 0, stream>>>(recv, ridx, sidx, WT + 16384, ez, denom, out0, out1);
}